// Round 5
// baseline (120.212 us; speedup 1.0000x reference)
//
#include <hip/hip_runtime.h>
#include <math.h>

#define NPH 8
#define NLUT 2048
#define SCALE ((float)(NLUT - 1))   // 2047 interpolation intervals over x in [0,1]

typedef float f32x4 __attribute__((ext_vector_type(4)));

// LUT in a module-scope device array: NO workspace usage (poison is
// unconditional — measured R1).  Entries 0..NLUT (2049 valid, padded to
// 2050 for float4 staging), (P, Q) pairs.
__device__ __align__(16) float2 g_lut[NLUT + 2];

// Full QSVT evaluation with the off-diagonal term sigma passed explicitly.
// f_alg(x, sigma) is a polynomial in sigma, so evaluating at +/-sigma splits
// even/odd parts: f = P(x) + sigma*Q(x).
__device__ __forceinline__ float qsvt_eval(float x, float sig,
                                           const float* cph, const float* sph) {
    float v0r, v0i, v1r, v1i;
    __sincosf(0.5f * x, &v1r, &v0r);   // [cos(x/2), sin(x/2)]
    v0i = 0.0f; v1i = 0.0f;
#pragma unroll
    for (int k = 0; k < NPH; ++k) {
        const float c = cph[k], sn = sph[k];
        const float a0r = v0r * c - v0i * sn;
        const float a0i = v0r * sn + v0i * c;
        const float a1r = v1r * c + v1i * sn;
        const float a1i = v1i * c - v1r * sn;
        if (k < NPH - 1) {
            v0r = x * a0r + sig * a1r;
            v0i = x * a0i + sig * a1i;
            v1r = sig * a0r - x * a1r;
            v1i = sig * a0i - x * a1i;
        } else {
            v0r = a0r; v0i = a0i; v1r = a1r; v1i = a1i;
        }
    }
    return (v0r * v0r + v0i * v0i) - (v1r * v1r + v1i * v1i);
}

// Kernel 1: build (P,Q) table. Arithmetic unchanged since R0 -> bit-identical.
__global__ void build_lut(const float* __restrict__ phi) {
    const int j = blockIdx.x * blockDim.x + threadIdx.x;
    if (j > NLUT) return;              // entries 0..NLUT inclusive (2049)
    float cph[NPH], sph[NPH];
#pragma unroll
    for (int k = 0; k < NPH; ++k) __sincosf(phi[k], &sph[k], &cph[k]);
    const int jj = (j < NLUT) ? j : (NLUT - 1);  // pad entry NLUT == entry NLUT-1
    float x = (float)jj * (1.0f / SCALE);
    float s = sqrtf(fmaxf(1.0f - x * x, 0.0f));
    if (s < 1e-3f) {            // endpoint x=1: sample at consistent (x~1, s=1e-3)
        s = 1e-3f;              // P,Q smooth -> sampling offset ~5e-7 in x negligible
        x = sqrtf(1.0f - s * s);
    }
    const float fp = qsvt_eval(x,  s, cph, sph);
    const float fm = qsvt_eval(x, -s, cph, sph);
    g_lut[j] = make_float2(0.5f * (fp + fm), (fp - fm) / (2.0f * s));
}

// Bit-identical to R1's interpolation.
__device__ __forceinline__ float lut_eval(float xin, const float2* __restrict__ lut) {
    const float x = fminf(fmaxf(xin, 0.0f), 1.0f);   // inputs are uniform [0,1)
    const float u = x * SCALE;                        // u in [0, 2047]
    const int i = (int)u;                             // trunc; i <= 2047
    const float fr = u - (float)i;
    const float2 e0 = lut[i];                         // adjacent pair -> ds_read2_b64
    const float2 e1 = lut[i + 1];
    const float s = sqrtf(fmaxf(fmaf(-x, x, 1.0f), 0.0f));
    const float p = fmaf(fr, e1.x - e0.x, e0.x);
    const float q = fmaf(fr, e1.y - e0.y, e0.y);
    return fmaf(s, q, p);
}

__device__ __forceinline__ f32x4 eval4(f32x4 v, const float2* __restrict__ lut) {
    f32x4 o;
    o.x = lut_eval(v.x, lut);
    o.y = lut_eval(v.y, lut);
    o.z = lut_eval(v.z, lut);
    o.w = lut_eval(v.w, lut);
    return o;
}

// Kernel 2: FLAT exact-fit map — no loops, no grid-stride.
// Block covers 512 contiguous float4 (two 256-wide panels); each thread:
//   issue 2 coalesced 16B loads -> stage LUT under them -> eval -> store -> exit.
// Latency hiding via wave churn (8 blocks/CU, 16.4 KB LDS).
__global__ __launch_bounds__(256, 8) void qsvt_main(const float* __restrict__ x,
                                                    float* __restrict__ out, int n) {
    __shared__ float2 lut[NLUT + 2];
    const int n4 = n >> 2;
    const f32x4* __restrict__ x4 = (const f32x4*)x;
    f32x4* __restrict__ o4 = (f32x4*)out;

    const int i0 = blockIdx.x * 512 + (int)threadIdx.x;   // panel 0
    const int i1 = i0 + 256;                              // panel 1
    const bool v0 = i0 < n4, v1 = i1 < n4;
    f32x4 a, b;
    if (v0) a = x4[i0];            // both HBM loads in flight before staging
    if (v1) b = x4[i1];

    // Stage 16.4 KB LUT from L2-resident g_lut while loads are outstanding.
    {
        const f32x4* __restrict__ src = (const f32x4*)g_lut;
        f32x4* dst = (f32x4*)lut;
        for (int j = threadIdx.x; j < (NLUT + 2) / 2; j += 256) dst[j] = src[j];
    }
    __syncthreads();

    if (v0) o4[i0] = eval4(a, lut);
    if (v1) o4[i1] = eval4(b, lut);

    const int tail = n & 3;
    if (tail && blockIdx.x == 0) {
        const int base = n4 << 2;
        if ((int)threadIdx.x < tail)
            out[base + threadIdx.x] = lut_eval(x[base + threadIdx.x], lut);
    }
}

extern "C" void kernel_launch(void* const* d_in, const int* in_sizes, int n_in,
                              void* d_out, int out_size, void* d_ws, size_t ws_size,
                              hipStream_t stream) {
    const float* x   = (const float*)d_in[0];   // x_chunk [B*CHUNK] fp32
    // d_in[1] = theta: RZ is unit-modulus diagonal -> cannot change <Z>; dead.
    const float* phi = (const float*)d_in[2];   // phi [8] fp32
    float* out = (float*)d_out;
    const int n = in_sizes[0];
    (void)d_ws; (void)ws_size;                  // workspace deliberately UNUSED

    build_lut<<<(NLUT + 1 + 63) / 64, 64, 0, stream>>>(phi);

    const int n4 = n >> 2;
    int blocks = (n4 + 511) / 512;              // bench shape: exactly 8192
    if (blocks < 1) blocks = 1;                 // keep tail path alive for tiny n
    qsvt_main<<<blocks, 256, 0, stream>>>(x, out, n);
}

// Round 6
// 118.370 us; speedup vs baseline: 1.0156x; 1.0156x over previous
//
#include <hip/hip_runtime.h>
#include <math.h>

#define NPH 8
#define NLUT 2048
#define SCALE ((float)(NLUT - 1))   // 2047 interpolation intervals over x in [0,1]

typedef float f32x4 __attribute__((ext_vector_type(4)));

// LUT in a module-scope device array: NO workspace usage (the 256 MiB ws
// poison is unconditional — measured R1 — but this keeps us independent of
// d_ws). Entries 0..NLUT (2049 valid, padded to 2050 for float4 staging).
__device__ __align__(16) float2 g_lut[NLUT + 2];

// Full QSVT evaluation with the off-diagonal term sigma passed explicitly.
// f_alg(x, sigma) is a polynomial in sigma, so evaluating at +/-sigma splits
// even/odd parts: f = P(x) + sigma*Q(x).
__device__ __forceinline__ float qsvt_eval(float x, float sig,
                                           const float* cph, const float* sph) {
    float v0r, v0i, v1r, v1i;
    __sincosf(0.5f * x, &v1r, &v0r);   // [cos(x/2), sin(x/2)]
    v0i = 0.0f; v1i = 0.0f;
#pragma unroll
    for (int k = 0; k < NPH; ++k) {
        const float c = cph[k], sn = sph[k];
        const float a0r = v0r * c - v0i * sn;
        const float a0i = v0r * sn + v0i * c;
        const float a1r = v1r * c + v1i * sn;
        const float a1i = v1i * c - v1r * sn;
        if (k < NPH - 1) {
            v0r = x * a0r + sig * a1r;
            v0i = x * a0i + sig * a1i;
            v1r = sig * a0r - x * a1r;
            v1i = sig * a0i - x * a1i;
        } else {
            v0r = a0r; v0i = a0i; v1r = a1r; v1i = a1i;
        }
    }
    return (v0r * v0r + v0i * v0i) - (v1r * v1r + v1i * v1i);
}

// Kernel 1: build (P,Q) table. Arithmetic unchanged since R0 -> bit-identical.
__global__ void build_lut(const float* __restrict__ phi) {
    const int j = blockIdx.x * blockDim.x + threadIdx.x;
    if (j > NLUT) return;              // entries 0..NLUT inclusive (2049)
    float cph[NPH], sph[NPH];
#pragma unroll
    for (int k = 0; k < NPH; ++k) __sincosf(phi[k], &sph[k], &cph[k]);
    const int jj = (j < NLUT) ? j : (NLUT - 1);  // pad entry NLUT == entry NLUT-1
    float x = (float)jj * (1.0f / SCALE);
    float s = sqrtf(fmaxf(1.0f - x * x, 0.0f));
    if (s < 1e-3f) {            // endpoint x=1: sample at consistent (x~1, s=1e-3)
        s = 1e-3f;              // P,Q smooth -> sampling offset ~5e-7 in x negligible
        x = sqrtf(1.0f - s * s);
    }
    const float fp = qsvt_eval(x,  s, cph, sph);
    const float fm = qsvt_eval(x, -s, cph, sph);
    g_lut[j] = make_float2(0.5f * (fp + fm), (fp - fm) / (2.0f * s));
}

// Bit-identical interpolation (f = P + s*Q with linear interp on P,Q).
__device__ __forceinline__ float lut_eval(float xin, const float2* __restrict__ lut) {
    const float x = fminf(fmaxf(xin, 0.0f), 1.0f);   // inputs are uniform [0,1)
    const float u = x * SCALE;                        // u in [0, 2047]
    const int i = (int)u;                             // trunc; i <= 2047
    const float fr = u - (float)i;
    const float2 e0 = lut[i];                         // adjacent pair -> ds_read2_b64
    const float2 e1 = lut[i + 1];
    const float s = sqrtf(fmaxf(fmaf(-x, x, 1.0f), 0.0f));
    const float p = fmaf(fr, e1.x - e0.x, e0.x);
    const float q = fmaf(fr, e1.y - e0.y, e0.y);
    return fmaf(s, q, p);
}

__device__ __forceinline__ f32x4 eval4(f32x4 v, const float2* __restrict__ lut) {
    f32x4 o;
    o.x = lut_eval(v.x, lut);
    o.y = lut_eval(v.y, lut);
    o.z = lut_eval(v.z, lut);
    o.w = lut_eval(v.w, lut);
    return o;
}

// Kernel 2: best-measured structure (R1, 117.7 us): stage 16.4 KB LUT in LDS
// (8 blocks/CU -> full 32-wave occupancy), then a plain float4 grid-stride
// gather+FMA map. A/B history: NT+stream-split hurt (R3), depth-1 prefetch
// null (R4), flat exact-fit null-minus (R5: 4x LUT re-staging). Latency is
// fully hidden by TLP (32 waves x 1 KB in flight >> Little's-law need);
// the kernel sits at the mixed-stream HBM floor.
__global__ __launch_bounds__(256, 8) void qsvt_main(const float* __restrict__ x,
                                                    float* __restrict__ out, int n) {
    __shared__ float2 lut[NLUT + 2];
    {
        const f32x4* __restrict__ src = (const f32x4*)g_lut;
        f32x4* dst = (f32x4*)lut;
        for (int j = threadIdx.x; j < (NLUT + 2) / 2; j += 256) dst[j] = src[j];
    }
    __syncthreads();

    const int n4 = n >> 2;
    const f32x4* __restrict__ x4 = (const f32x4*)x;
    f32x4* __restrict__ o4 = (f32x4*)out;
    const int idx = blockIdx.x * blockDim.x + threadIdx.x;
    const int stride = gridDim.x * blockDim.x;
    for (int i = idx; i < n4; i += stride) {
        o4[i] = eval4(x4[i], lut);
    }
    const int tail = n & 3;
    if (tail) {
        const int base = n4 << 2;
        if (idx < tail) out[base + idx] = lut_eval(x[base + idx], lut);
    }
}

extern "C" void kernel_launch(void* const* d_in, const int* in_sizes, int n_in,
                              void* d_out, int out_size, void* d_ws, size_t ws_size,
                              hipStream_t stream) {
    const float* x   = (const float*)d_in[0];   // x_chunk [B*CHUNK] fp32
    // d_in[1] = theta: RZ is unit-modulus diagonal -> cannot change <Z>; dead.
    const float* phi = (const float*)d_in[2];   // phi [8] fp32
    float* out = (float*)d_out;
    const int n = in_sizes[0];
    (void)d_ws; (void)ws_size;                  // workspace deliberately UNUSED

    build_lut<<<(NLUT + 1 + 63) / 64, 64, 0, stream>>>(phi);
    // 2048 blocks = 8 blocks/CU (16.4 KB LDS, 32-wave cap) x 256 CUs.
    qsvt_main<<<2048, 256, 0, stream>>>(x, out, n);
}